// Round 6
// baseline (4460.715 us; speedup 1.0000x reference)
//
#include <hip/hip_runtime.h>
#include <math.h>

#define B_   64
#define S_   512
#define E_   256
#define H_   256
#define G4H_ 1024
#define NT_  24

// ---- workspace layout (float-element offsets) ----
// hbuf  : [2 slot][2 dir][256 k][64 b] x {float h, uint tag} = 131072 f (zeroed)
// cstate: [2][B][H]; emisF/emisB: [B][S][NT]; hout_c then xpre_c (tc-sized)
static const size_t HBUF_OFF  = 0;
static const size_t CST_OFF   = 131072;
static const size_t EMF_OFF   = 163840;
static const size_t EMB_OFF   = 950272;
static const size_t HOUT_OFF  = 1736704;

__device__ __forceinline__ float sigmoidf_(float x) {
  return 1.0f / (1.0f + expf(-x));
}

// ============================================================================
// K1: xpre_c[d][lt][b][:] = emb[x[b][tok]] @ Wih_d^T + (bih_d + bhh_d)
// ============================================================================
__global__ __launch_bounds__(256) void k1_xpre(
    const int* __restrict__ x, const float* __restrict__ emb,
    const float* __restrict__ Wih_f, const float* __restrict__ bih_f,
    const float* __restrict__ bhh_f, const float* __restrict__ Wih_b,
    const float* __restrict__ bih_b, const float* __restrict__ bhh_b,
    float* __restrict__ xpre_c, int chunk, int tc)
{
  __shared__ float As[32][132];   // [k][m]
  __shared__ float Bs[32][132];   // [k][n]
  __shared__ int   xt[128];

  const int tid = threadIdx.x;
  const int wg  = blockIdx.x;
  const int per_dir = 4 * tc;
  const int d   = wg / per_dir;
  const int rem = wg % per_dir;
  const int m0  = (rem >> 3) * 128;
  const int n0  = (rem & 7) * 128;
  const int t0  = chunk * tc;

  const float* Wih = d ? Wih_b : Wih_f;
  const float* bih = d ? bih_b : bih_f;
  const float* bhh = d ? bhh_b : bhh_f;

  if (tid < 128) {
    int m = m0 + tid;
    int lt = m >> 6, b = m & 63;
    int tok = d ? (S_ - 1 - (t0 + lt)) : (t0 + lt);
    xt[tid] = x[b * S_ + tok];
  }
  __syncthreads();

  float acc[8][8];
#pragma unroll
  for (int i = 0; i < 8; ++i)
#pragma unroll
    for (int j = 0; j < 8; ++j) acc[i][j] = 0.0f;

  const int mt8 = tid & 15;
  const int nt8 = tid >> 4;
  const int q = tid & 7, rbase = tid >> 3;

  for (int kc = 0; kc < 8; ++kc) {
    const int k0 = kc * 32;
#pragma unroll
    for (int i = 0; i < 4; ++i) {
      int row = rbase + i * 32;
      float4 a = *(const float4*)(emb + (long)xt[row] * E_ + k0 + q * 4);
      As[q * 4 + 0][row] = a.x; As[q * 4 + 1][row] = a.y;
      As[q * 4 + 2][row] = a.z; As[q * 4 + 3][row] = a.w;
      float4 w = *(const float4*)(Wih + (long)(n0 + row) * E_ + k0 + q * 4);
      Bs[q * 4 + 0][row] = w.x; Bs[q * 4 + 1][row] = w.y;
      Bs[q * 4 + 2][row] = w.z; Bs[q * 4 + 3][row] = w.w;
    }
    __syncthreads();
#pragma unroll
    for (int k = 0; k < 32; ++k) {
      float4 a0 = *(float4*)&As[k][mt8 * 8];
      float4 a1 = *(float4*)&As[k][mt8 * 8 + 4];
      float4 b0 = *(float4*)&Bs[k][nt8 * 8];
      float4 b1 = *(float4*)&Bs[k][nt8 * 8 + 4];
      float am[8] = {a0.x, a0.y, a0.z, a0.w, a1.x, a1.y, a1.z, a1.w};
      float bn[8] = {b0.x, b0.y, b0.z, b0.w, b1.x, b1.y, b1.z, b1.w};
#pragma unroll
      for (int i = 0; i < 8; ++i)
#pragma unroll
        for (int j = 0; j < 8; ++j) acc[i][j] = fmaf(am[i], bn[j], acc[i][j]);
    }
    __syncthreads();
  }

  float bias[8];
  {
    float4 u0 = *(const float4*)(bih + n0 + nt8 * 8);
    float4 u1 = *(const float4*)(bih + n0 + nt8 * 8 + 4);
    float4 v0 = *(const float4*)(bhh + n0 + nt8 * 8);
    float4 v1 = *(const float4*)(bhh + n0 + nt8 * 8 + 4);
    bias[0] = u0.x + v0.x; bias[1] = u0.y + v0.y; bias[2] = u0.z + v0.z;
    bias[3] = u0.w + v0.w; bias[4] = u1.x + v1.x; bias[5] = u1.y + v1.y;
    bias[6] = u1.z + v1.z; bias[7] = u1.w + v1.w;
  }
#pragma unroll
  for (int i = 0; i < 8; ++i) {
    int m = m0 + mt8 * 8 + i;
    int lt = m >> 6, b = m & 63;
    float* o = xpre_c + ((size_t)(d * tc + lt) * B_ + b) * G4H_ + n0 + nt8 * 8;
    float4 r0, r1;
    r0.x = acc[i][0] + bias[0]; r0.y = acc[i][1] + bias[1];
    r0.z = acc[i][2] + bias[2]; r0.w = acc[i][3] + bias[3];
    r1.x = acc[i][4] + bias[4]; r1.y = acc[i][5] + bias[5];
    r1.z = acc[i][6] + bias[6]; r1.w = acc[i][7] + bias[7];
    *(float4*)o = r0;
    *(float4*)(o + 4) = r1;
  }
}

// ============================================================================
// K2: biLSTM recurrence, tag-in-data sync, FULLY WAVE-AUTONOMOUS step loop:
// zero __syncthreads. Wave w of WG (d,bg,s) owns batches bw=bg*16+4w..+3 for
// all 32 r-rows: in-wave 8-way k-split (kg=lane>>3, rp=lane&7 -> 4 r's,
// 128 weight VGPRs/thread), butterfly shfl reduce, per-wave gbuf transpose
// (same-wave lgkm order), pointwise in lanes 0-31, immediate publish.
// Exchange closure = {wave w of the 32 s-WGs}: barrier + wave-skew removed
// from the critical path. LDS reads use rotated k-order (weights permuted at
// load to keep register indices compile-time) -> 2-way conflicts only.
// ============================================================================
__global__ __launch_bounds__(256, 1) void k2_lstm(
    const float* __restrict__ Whh_f, const float* __restrict__ Whh_b,
    const float* __restrict__ xpre_c, float* __restrict__ hout_c,
    unsigned long long* hbuf, float* cstate, int chunk, int tc)
{
  __shared__ float hTb[4][4][264];   // [wave][b_local][k + pad] (16,896 B)
  __shared__ float gbuf[4][4][36];   // [wave][b_local][r + pad] ( 2,304 B)

  const int tid  = threadIdx.x;
  const int wg   = blockIdx.x;
  const int d    = wg >> 7;
  const int bg   = (wg >> 5) & 3;
  const int s    = wg & 31;
  const float* Whh = d ? Whh_b : Whh_f;

  const int w    = tid >> 6;          // wave 0..3
  const int lane = tid & 63;
  const int bw   = bg * 16 + 4 * w;   // wave's batch base (4 batches)
  // GEMM mapping: kg = 32-k chunk owner, rp -> 4 consecutive r's
  const int kg = lane >> 3, rp = lane & 7;
  // staging mapping: sb = local batch, ksec = 16-k section
  const int sb = lane & 3, ksec = lane >> 2;
  // pointwise mapping (lanes 0..31): pb = local batch, pj = local row
  const int pb = (lane >> 3) & 3, pj = lane & 7;

  // hoist Whh tile into VGPRs; slot q holds k = kg*32 + ((q+2kg)&7)*4 + kk
  // (read-rotation permutation folded into the load)
  float wreg[4][32];
#pragma unroll
  for (int ri = 0; ri < 4; ++ri) {
    int r = rp * 4 + ri, g = r >> 3, j = r & 7;
    const float* src = Whh + ((size_t)(g * H_ + s * 8 + j)) * H_ + kg * 32;
#pragma unroll
    for (int q = 0; q < 8; ++q) {
      int qs = (q + kg * 2) & 7;
      float4 v = *(const float4*)(src + qs * 4);
      wreg[ri][q * 4 + 0] = v.x; wreg[ri][q * 4 + 1] = v.y;
      wreg[ri][q * 4 + 2] = v.z; wreg[ri][q * 4 + 3] = v.w;
    }
  }

  float c_reg = 0.0f;
  if (chunk > 0 && lane < 32)
    c_reg = cstate[((size_t)d * B_ + bw + pb) * H_ + s * 8 + pj];

  for (int tt = 1; tt <= tc; ++tt) {
    const int t  = chunk * tc + tt;   // global step 1..512
    const int lt = tt - 1;

    // xpre prefetch (independent of h -> overlaps the poll)
    float xp[4];
    if (lane < 32) {
#pragma unroll
      for (int g = 0; g < 4; ++g)
        xp[g] = xpre_c[((size_t)(d * tc + lt) * B_ + bw + pb) * G4H_ +
                       g * H_ + s * 8 + pj];
    }

    // stage h(t-1) for this wave's 4 batches: 16 tagged entries/lane
    {
      const unsigned expt = (unsigned)(t - 1);
      const unsigned long long* hb =
          hbuf + ((size_t)(((t - 1) & 1) * 2 + d)) * (256 * 64);
      const size_t a0 = (size_t)(ksec * 16) * 64 + (bw + sb);
      unsigned long long e[16];
#pragma unroll
      for (int i = 0; i < 16; ++i)
        e[i] = __hip_atomic_load(hb + a0 + (size_t)i * 64,
                                 __ATOMIC_RELAXED, __HIP_MEMORY_SCOPE_AGENT);
      int lim = 0;
      while (true) {
        unsigned bad = 0;
#pragma unroll
        for (int i = 0; i < 16; ++i)
          if ((unsigned)(e[i] >> 32) != expt) bad |= (1u << i);
        if (bad == 0) break;
        if (++lim > (1 << 18)) break;   // deadlock safety
#pragma unroll
        for (int i = 0; i < 16; ++i)
          if (bad & (1u << i))
            e[i] = __hip_atomic_load(hb + a0 + (size_t)i * 64,
                                     __ATOMIC_RELAXED,
                                     __HIP_MEMORY_SCOPE_AGENT);
      }
#pragma unroll
      for (int n = 0; n < 4; ++n) {
        float4 v;
        v.x = __uint_as_float((unsigned)e[4 * n + 0]);
        v.y = __uint_as_float((unsigned)e[4 * n + 1]);
        v.z = __uint_as_float((unsigned)e[4 * n + 2]);
        v.w = __uint_as_float((unsigned)e[4 * n + 3]);
        *(float4*)&hTb[w][sb][ksec * 16 + n * 4] = v;
      }
    }
    // no barrier anywhere: all LDS deps are same-wave (in-order DS pipe)

    // GEMM: acc[b][ri] += h[b][k] * W[k][r] over k in [kg*32, kg*32+32)
    float acc[4][4];
#pragma unroll
    for (int b = 0; b < 4; ++b)
#pragma unroll
      for (int ri = 0; ri < 4; ++ri) acc[b][ri] = 0.0f;
#pragma unroll
    for (int b = 0; b < 4; ++b) {
      const float* hrow = &hTb[w][b][kg * 32];
#pragma unroll
      for (int q = 0; q < 8; ++q) {
        int qs = (q + kg * 2) & 7;          // rotated col: 2-way banks max
        float4 h4 = *(const float4*)(hrow + qs * 4);
#pragma unroll
        for (int kk = 0; kk < 4; ++kk) {
          const float hv = kk == 0 ? h4.x : kk == 1 ? h4.y
                         : kk == 2 ? h4.z : h4.w;
#pragma unroll
          for (int ri = 0; ri < 4; ++ri)
            acc[b][ri] = fmaf(hv, wreg[ri][q * 4 + kk], acc[b][ri]);
        }
      }
    }
    // butterfly reduce across the 8 kg groups (in-register, no LDS)
#pragma unroll
    for (int b = 0; b < 4; ++b)
#pragma unroll
      for (int ri = 0; ri < 4; ++ri) {
        float v = acc[b][ri];
        v += __shfl_xor(v, 8, 64);
        v += __shfl_xor(v, 16, 64);
        v += __shfl_xor(v, 32, 64);
        acc[b][ri] = v;
      }
    if (kg == 0) {   // lanes 0..7: write full sums, conflict-free b128
#pragma unroll
      for (int b = 0; b < 4; ++b)
        *(float4*)&gbuf[w][b][rp * 4] =
            make_float4(acc[b][0], acc[b][1], acc[b][2], acc[b][3]);
    }

    if (lane < 32) {
      const int bglob = bw + pb;
      float gsum[4];
#pragma unroll
      for (int g = 0; g < 4; ++g)
        gsum[g] = xp[g] + gbuf[w][pb][g * 8 + pj];
      float si = sigmoidf_(gsum[0]);
      float sf = sigmoidf_(gsum[1]);
      float tg = tanhf(gsum[2]);
      float so = sigmoidf_(gsum[3]);
      c_reg = sf * c_reg + si * tg;
      float h = so * tanhf(c_reg);
      unsigned long long pk =
          (((unsigned long long)(unsigned)t) << 32) |
          (unsigned long long)__float_as_uint(h);
      __hip_atomic_store(hbuf + ((size_t)((t & 1) * 2 + d)) * (256 * 64) +
                             (size_t)(s * 8 + pj) * 64 + bglob,
                         pk, __ATOMIC_RELAXED, __HIP_MEMORY_SCOPE_AGENT);
      hout_c[((size_t)(d * tc + lt) * B_ + bglob) * H_ + s * 8 + pj] = h;
    }
  }

  if (lane < 32)
    cstate[((size_t)d * B_ + bw + pb) * H_ + s * 8 + pj] = c_reg;
}

// ============================================================================
// K3: both directions' emission contributions in one launch.
// ============================================================================
__global__ __launch_bounds__(256) void k3_emis(
    const float* __restrict__ hout_c, const float* __restrict__ Wout,
    float* __restrict__ emisF, float* __restrict__ emisB, int chunk, int tc)
{
  __shared__ float hh[8][264];
  const int tid = threadIdx.x;
  const int nt8 = tc >> 3;
  const int per_d = 64 * nt8;
  const int d   = blockIdx.x / per_d;
  const int rem = blockIdx.x % per_d;
  const int b   = rem / nt8;
  const int lt0 = (rem % nt8) * 8;
  float* emisX = d ? emisB : emisF;
  {
    int r = tid >> 5, q = tid & 31;
    const float* src = hout_c + ((size_t)(d * tc + lt0 + r) * B_ + b) * H_;
#pragma unroll
    for (int i = 0; i < 2; ++i) {
      int f4i = q + 32 * i;
      *(float4*)&hh[r][f4i * 4] = *(const float4*)(src + f4i * 4);
    }
  }
  __syncthreads();
  if (tid < 192) {
    int r = tid / 24, tag = tid % 24;
    float acc = 0.0f;
    const float* w = Wout + (size_t)tag * 512 + d * 256;
#pragma unroll 4
    for (int k4 = 0; k4 < 64; ++k4) {
      float4 wv = *(const float4*)(w + k4 * 4);
      float4 hv = *(const float4*)&hh[r][k4 * 4];
      acc = fmaf(wv.x, hv.x, acc);
      acc = fmaf(wv.y, hv.y, acc);
      acc = fmaf(wv.z, hv.z, acc);
      acc = fmaf(wv.w, hv.w, acc);
    }
    int lt = lt0 + r;
    int tok = d ? (S_ - 1 - (chunk * tc + lt)) : (chunk * tc + lt);
    emisX[((size_t)b * S_ + tok) * NT_ + tag] = acc;
  }
}

// ============================================================================
// K4: Viterbi forward + backtrack; 1 wave per batch element.
// ============================================================================
__global__ __launch_bounds__(64) void k4_viterbi(
    const float* __restrict__ emisF, const float* __restrict__ emisB,
    const float* __restrict__ bout, const unsigned char* __restrict__ mb,
    const float* __restrict__ trans, const float* __restrict__ startv,
    const float* __restrict__ endv, int* __restrict__ outp)
{
  __shared__ float tl[24 * 25];
  __shared__ float sc[24];
  __shared__ float fin[24];
  __shared__ unsigned char hist[511 * 24];
  const int b = blockIdx.x;
  const int tid = threadIdx.x;
  const int is_bool = mb[1];

  for (int i = tid; i < 576; i += 64) tl[(i / 24) * 25 + (i % 24)] = trans[i];
  if (tid < 24) {
    size_t e0 = (size_t)b * S_ * NT_ + tid;
    sc[tid] = startv[tid] + (emisF[e0] + emisB[e0] + bout[tid]);
  }
  __syncthreads();

  for (int t = 1; t < S_; ++t) {
    float best = -3.4e38f, scj = 0.f;
    int idx = 0;
    int m;
    {
      int mi = b * S_ + t;
      m = is_bool ? (int)mb[mi] : (int)mb[mi << 2];
    }
    if (tid < 24) {
      size_t ei = ((size_t)b * S_ + t) * NT_ + tid;
      float e = emisF[ei] + emisB[ei] + bout[tid];
      for (int i = 0; i < 24; ++i) {
        float v = (sc[i] + tl[i * 25 + tid]) + e;   // ref assoc order
        if (v > best) { best = v; idx = i; }
      }
      scj = sc[tid];
    }
    __syncthreads();
    if (tid < 24) {
      sc[tid] = m ? best : scj;
      hist[(t - 1) * 24 + tid] = (unsigned char)(m ? idx : tid);
    }
    __syncthreads();
  }
  if (tid < 24) fin[tid] = sc[tid] + endv[tid];
  __syncthreads();
  if (tid == 0) {
    int tag = 0; float best = fin[0];
    for (int i = 1; i < 24; ++i)
      if (fin[i] > best) { best = fin[i]; tag = i; }
    outp[b * S_ + (S_ - 1)] = tag;
    for (int tt = S_ - 2; tt >= 0; --tt) {
      tag = hist[tt * 24 + tag];
      outp[b * S_ + tt] = tag;
    }
  }
}

// ============================================================================
extern "C" void kernel_launch(void* const* d_in, const int* in_sizes, int n_in,
                              void* d_out, int out_size, void* d_ws,
                              size_t ws_size, hipStream_t stream)
{
  const int*   x      = (const int*)d_in[0];
  const unsigned char* maskb = (const unsigned char*)d_in[1];
  const float* emb    = (const float*)d_in[2];
  const float* Wih_f  = (const float*)d_in[3];
  const float* Whh_f  = (const float*)d_in[4];
  const float* bih_f  = (const float*)d_in[5];
  const float* bhh_f  = (const float*)d_in[6];
  const float* Wih_b  = (const float*)d_in[7];
  const float* Whh_b  = (const float*)d_in[8];
  const float* bih_b  = (const float*)d_in[9];
  const float* bhh_b  = (const float*)d_in[10];
  const float* Wout   = (const float*)d_in[11];
  const float* bout   = (const float*)d_in[12];
  const float* trans  = (const float*)d_in[13];
  const float* startv = (const float*)d_in[14];
  const float* endv   = (const float*)d_in[15];

  int tc = 8;
  {
    const int cand[6] = {512, 256, 128, 64, 32, 16};
    for (int i = 0; i < 6; ++i) {
      size_t needF = HOUT_OFF + (size_t)cand[i] * (2 * B_ * H_ + 2 * B_ * G4H_);
      if (needF * sizeof(float) <= ws_size) { tc = cand[i]; break; }
    }
  }
  const int nc = S_ / tc;

  float* ws     = (float*)d_ws;
  unsigned long long* hbuf = (unsigned long long*)(ws + HBUF_OFF);
  float* cstate = ws + CST_OFF;
  float* emisF  = ws + EMF_OFF;
  float* emisB  = ws + EMB_OFF;
  float* hout_c = ws + HOUT_OFF;
  float* xpre_c = hout_c + (size_t)tc * 2 * B_ * H_;

  // zero hbuf (h(0)=0, tags=0); ws is re-poisoned 0xAA before every launch
  hipMemsetAsync(d_ws, 0, 131072 * sizeof(float), stream);

  for (int c = 0; c < nc; ++c) {
    hipLaunchKernelGGL(k1_xpre, dim3(8 * tc), dim3(256), 0, stream,
                       x, emb, Wih_f, bih_f, bhh_f, Wih_b, bih_b, bhh_b,
                       xpre_c, c, tc);
    hipLaunchKernelGGL(k2_lstm, dim3(256), dim3(256), 0, stream,
                       Whh_f, Whh_b, xpre_c, hout_c, hbuf, cstate, c, tc);
    hipLaunchKernelGGL(k3_emis, dim3(2 * 64 * (tc / 8)), dim3(256), 0, stream,
                       hout_c, Wout, emisF, emisB, c, tc);
  }
  hipLaunchKernelGGL(k4_viterbi, dim3(64), dim3(64), 0, stream,
                     emisF, emisB, bout, maskb, trans, startv, endv,
                     (int*)d_out);
}

// Round 8
// 3200.566 us; speedup vs baseline: 1.3937x; 1.3937x over previous
//
#include <hip/hip_runtime.h>
#include <math.h>

#define B_   64
#define S_   512
#define E_   256
#define H_   256
#define G4H_ 1024
#define NT_  24

// ---- workspace layout (float-element offsets) ----
// hbuf  : [2 slot][2 dir][256 k][64 b] x {float h, uint tag} = 131072 f (zeroed)
// cstate: [2][B][H]; emisF/emisB: [B][S][NT]; hout_c then xpre_c (tc-sized)
static const size_t HBUF_OFF  = 0;
static const size_t CST_OFF   = 131072;
static const size_t EMF_OFF   = 163840;
static const size_t EMB_OFF   = 950272;
static const size_t HOUT_OFF  = 1736704;

__device__ __forceinline__ float sigmoidf_(float x) {
  return 1.0f / (1.0f + expf(-x));
}

// LDS-only barrier: orders ds ops (lgkmcnt) + syncs, but does NOT drain
// vmcnt — in-flight global prefetch loads keep flying across it.
__device__ __forceinline__ void barrier_lds_() {
  asm volatile("s_waitcnt lgkmcnt(0)\n\ts_barrier" ::: "memory");
}

// ============================================================================
// K1: xpre_c[d][lt][b][:] = emb[x[b][tok]] @ Wih_d^T + (bih_d + bhh_d)
// ============================================================================
__global__ __launch_bounds__(256) void k1_xpre(
    const int* __restrict__ x, const float* __restrict__ emb,
    const float* __restrict__ Wih_f, const float* __restrict__ bih_f,
    const float* __restrict__ bhh_f, const float* __restrict__ Wih_b,
    const float* __restrict__ bih_b, const float* __restrict__ bhh_b,
    float* __restrict__ xpre_c, int chunk, int tc)
{
  __shared__ float As[32][132];   // [k][m]
  __shared__ float Bs[32][132];   // [k][n]
  __shared__ int   xt[128];

  const int tid = threadIdx.x;
  const int wg  = blockIdx.x;
  const int per_dir = 4 * tc;
  const int d   = wg / per_dir;
  const int rem = wg % per_dir;
  const int m0  = (rem >> 3) * 128;
  const int n0  = (rem & 7) * 128;
  const int t0  = chunk * tc;

  const float* Wih = d ? Wih_b : Wih_f;
  const float* bih = d ? bih_b : bih_f;
  const float* bhh = d ? bhh_b : bhh_f;

  if (tid < 128) {
    int m = m0 + tid;
    int lt = m >> 6, b = m & 63;
    int tok = d ? (S_ - 1 - (t0 + lt)) : (t0 + lt);
    xt[tid] = x[b * S_ + tok];
  }
  __syncthreads();

  float acc[8][8];
#pragma unroll
  for (int i = 0; i < 8; ++i)
#pragma unroll
    for (int j = 0; j < 8; ++j) acc[i][j] = 0.0f;

  const int mt8 = tid & 15;
  const int nt8 = tid >> 4;
  const int q = tid & 7, rbase = tid >> 3;

  for (int kc = 0; kc < 8; ++kc) {
    const int k0 = kc * 32;
#pragma unroll
    for (int i = 0; i < 4; ++i) {
      int row = rbase + i * 32;
      float4 a = *(const float4*)(emb + (long)xt[row] * E_ + k0 + q * 4);
      As[q * 4 + 0][row] = a.x; As[q * 4 + 1][row] = a.y;
      As[q * 4 + 2][row] = a.z; As[q * 4 + 3][row] = a.w;
      float4 w = *(const float4*)(Wih + (long)(n0 + row) * E_ + k0 + q * 4);
      Bs[q * 4 + 0][row] = w.x; Bs[q * 4 + 1][row] = w.y;
      Bs[q * 4 + 2][row] = w.z; Bs[q * 4 + 3][row] = w.w;
    }
    __syncthreads();
#pragma unroll
    for (int k = 0; k < 32; ++k) {
      float4 a0 = *(float4*)&As[k][mt8 * 8];
      float4 a1 = *(float4*)&As[k][mt8 * 8 + 4];
      float4 b0 = *(float4*)&Bs[k][nt8 * 8];
      float4 b1 = *(float4*)&Bs[k][nt8 * 8 + 4];
      float am[8] = {a0.x, a0.y, a0.z, a0.w, a1.x, a1.y, a1.z, a1.w};
      float bn[8] = {b0.x, b0.y, b0.z, b0.w, b1.x, b1.y, b1.z, b1.w};
#pragma unroll
      for (int i = 0; i < 8; ++i)
#pragma unroll
        for (int j = 0; j < 8; ++j) acc[i][j] = fmaf(am[i], bn[j], acc[i][j]);
    }
    __syncthreads();
  }

  float bias[8];
  {
    float4 u0 = *(const float4*)(bih + n0 + nt8 * 8);
    float4 u1 = *(const float4*)(bih + n0 + nt8 * 8 + 4);
    float4 v0 = *(const float4*)(bhh + n0 + nt8 * 8);
    float4 v1 = *(const float4*)(bhh + n0 + nt8 * 8 + 4);
    bias[0] = u0.x + v0.x; bias[1] = u0.y + v0.y; bias[2] = u0.z + v0.z;
    bias[3] = u0.w + v0.w; bias[4] = u1.x + v1.x; bias[5] = u1.y + v1.y;
    bias[6] = u1.z + v1.z; bias[7] = u1.w + v1.w;
  }
#pragma unroll
  for (int i = 0; i < 8; ++i) {
    int m = m0 + mt8 * 8 + i;
    int lt = m >> 6, b = m & 63;
    float* o = xpre_c + ((size_t)(d * tc + lt) * B_ + b) * G4H_ + n0 + nt8 * 8;
    float4 r0, r1;
    r0.x = acc[i][0] + bias[0]; r0.y = acc[i][1] + bias[1];
    r0.z = acc[i][2] + bias[2]; r0.w = acc[i][3] + bias[3];
    r1.x = acc[i][4] + bias[4]; r1.y = acc[i][5] + bias[5];
    r1.z = acc[i][6] + bias[6]; r1.w = acc[i][7] + bias[7];
    *(float4*)o = r0;
    *(float4*)(o + 4) = r1;
  }
}

// ============================================================================
// K2: biLSTM recurrence = round-5 structure (best measured: 128B-coalesced
// staging, weights in VGPRs, part[] parity-double-buffered, one barrier)
// PLUS cross-step prefetch: h(t) loads are issued right after h(t-1) staging
// and kept in flight through GEMM/barrier/pointwise (the barrier is an
// LDS-only s_waitcnt lgkmcnt(0);s_barrier — it does NOT drain vmcnt).
// Safe by ring induction: any reader of slot t&1 at that time wants tag t.
// 256 WGs = dir(2) x batch-group(4 x 16b) x h-slice(32 x 8 rows), 1 WG/CU.
// ============================================================================
__global__ __launch_bounds__(256, 1) void k2_lstm(
    const float* __restrict__ Whh_f, const float* __restrict__ Whh_b,
    const float* __restrict__ xpre_c, float* __restrict__ hout_c,
    unsigned long long* hbuf, float* cstate, int chunk, int tc)
{
  __shared__ float hTb[16][260];         // [b_local][k + pad]
  __shared__ float part[2][4][16][36];   // [parity][wave][b][r]

  const int tid = threadIdx.x;
  const int wg  = blockIdx.x;
  const int d   = wg >> 7;
  const int bg  = (wg >> 5) & 3;
  const int s   = wg & 31;
  const int b0  = bg * 16;
  const float* Whh = d ? Whh_b : Whh_f;

  const int w     = tid >> 6;           // wave 0..3
  const int lane  = tid & 63;
  const int bl16  = lane & 15;          // staging batch
  const int kb    = lane >> 4;          // 0..3
  const int kbase = w * 64 + kb * 16;   // staging k range [kbase, kbase+16)
  const int ks    = tid >> 5;           // GEMM k-chunk [32ks, 32ks+32)
  const int tl    = tid & 31, bt = tl & 3, rt = tl >> 2;
  const int pbl   = tid >> 3, pj = tid & 7;   // pointwise mapping (tid<128)

  // hoist this thread's Whh tile into registers (fixed for all steps)
  float wreg[4][32];
#pragma unroll
  for (int ri = 0; ri < 4; ++ri) {
    int r = rt * 4 + ri, g = r >> 3, j = r & 7;
    const float* src = Whh + ((size_t)(g * H_ + s * 8 + j)) * H_ + ks * 32;
#pragma unroll
    for (int q = 0; q < 8; ++q) {
      float4 v = *(const float4*)(src + q * 4);
      wreg[ri][q * 4 + 0] = v.x; wreg[ri][q * 4 + 1] = v.y;
      wreg[ri][q * 4 + 2] = v.z; wreg[ri][q * 4 + 3] = v.w;
    }
  }

  float c_reg = 0.0f;
  if (chunk > 0 && tid < 128)
    c_reg = cstate[((size_t)d * B_ + b0 + pbl) * H_ + s * 8 + pj];

  const size_t a0 = (size_t)kbase * 64 + b0 + bl16;   // lane's entry base
  unsigned long long e[16];

  // pre-issue loads for the first step's h(t-1)
  {
    const unsigned long long* hb =
        hbuf + ((size_t)(((chunk * tc) & 1) * 2 + d)) * (256 * 64);
#pragma unroll
    for (int i = 0; i < 16; ++i)
      e[i] = __hip_atomic_load(hb + a0 + (size_t)i * 64,
                               __ATOMIC_RELAXED, __HIP_MEMORY_SCOPE_AGENT);
  }

  for (int tt = 1; tt <= tc; ++tt) {
    const int t  = chunk * tc + tt;   // global step 1..512
    const int lt = tt - 1;
    const int p  = tt & 1;

    // xpre prefetch (independent of h)
    float xp[4];
    if (tid < 128) {
#pragma unroll
      for (int g = 0; g < 4; ++g)
        xp[g] = xpre_c[((size_t)(d * tc + lt) * B_ + b0 + pbl) * G4H_ +
                       g * H_ + s * 8 + pj];
    }

    // verify prefetched h(t-1) entries; retry stale ones
    {
      const unsigned expt = (unsigned)(t - 1);
      const unsigned long long* hb =
          hbuf + ((size_t)(((t - 1) & 1) * 2 + d)) * (256 * 64);
      int lim = 0;
      while (true) {
        unsigned bad = 0;
#pragma unroll
        for (int i = 0; i < 16; ++i)
          if ((unsigned)(e[i] >> 32) != expt) bad |= (1u << i);
        if (bad == 0) break;
        if (++lim > (1 << 18)) break;   // deadlock safety
#pragma unroll
        for (int i = 0; i < 16; ++i)
          if (bad & (1u << i))
            e[i] = __hip_atomic_load(hb + a0 + (size_t)i * 64,
                                     __ATOMIC_RELAXED,
                                     __HIP_MEMORY_SCOPE_AGENT);
      }
      float4 v0, v1, v2, v3;
      v0.x = __uint_as_float((unsigned)e[0]);  v0.y = __uint_as_float((unsigned)e[1]);
      v0.z = __uint_as_float((unsigned)e[2]);  v0.w = __uint_as_float((unsigned)e[3]);
      v1.x = __uint_as_float((unsigned)e[4]);  v1.y = __uint_as_float((unsigned)e[5]);
      v1.z = __uint_as_float((unsigned)e[6]);  v1.w = __uint_as_float((unsigned)e[7]);
      v2.x = __uint_as_float((unsigned)e[8]);  v2.y = __uint_as_float((unsigned)e[9]);
      v2.z = __uint_as_float((unsigned)e[10]); v2.w = __uint_as_float((unsigned)e[11]);
      v3.x = __uint_as_float((unsigned)e[12]); v3.y = __uint_as_float((unsigned)e[13]);
      v3.z = __uint_as_float((unsigned)e[14]); v3.w = __uint_as_float((unsigned)e[15]);
      *(float4*)&hTb[bl16][kbase +  0] = v0;
      *(float4*)&hTb[bl16][kbase +  4] = v1;
      *(float4*)&hTb[bl16][kbase +  8] = v2;
      *(float4*)&hTb[bl16][kbase + 12] = v3;
    }

    // PREFETCH next step's h(t): issued now, stays in flight through
    // GEMM + barrier + pointwise (barrier below is lgkm-only).
    {
      const unsigned long long* hbn =
          hbuf + ((size_t)((t & 1) * 2 + d)) * (256 * 64);
#pragma unroll
      for (int i = 0; i < 16; ++i)
        e[i] = __hip_atomic_load(hbn + a0 + (size_t)i * 64,
                                 __ATOMIC_RELAXED, __HIP_MEMORY_SCOPE_AGENT);
    }
    // no barrier: wave GEMM-reads only its own staged k-columns

    // GEMM: acc[bi][ri] += h[b][k] * W[k][r], weights from VGPRs
    float acc[4][4];
#pragma unroll
    for (int bi = 0; bi < 4; ++bi)
#pragma unroll
      for (int ri = 0; ri < 4; ++ri) acc[bi][ri] = 0.0f;
#pragma unroll
    for (int kq = 0; kq < 8; ++kq) {
      const int k0 = ks * 32 + kq * 4;
      float4 h4[4];
#pragma unroll
      for (int bi = 0; bi < 4; ++bi)
        h4[bi] = *(float4*)&hTb[bt * 4 + bi][k0];
#pragma unroll
      for (int kk = 0; kk < 4; ++kk) {
#pragma unroll
        for (int bi = 0; bi < 4; ++bi) {
          const float hv = kk == 0 ? h4[bi].x : kk == 1 ? h4[bi].y
                         : kk == 2 ? h4[bi].z : h4[bi].w;
#pragma unroll
          for (int ri = 0; ri < 4; ++ri)
            acc[bi][ri] = fmaf(hv, wreg[ri][kq * 4 + kk], acc[bi][ri]);
        }
      }
    }
    // reduce the two half-wave k-chunks, publish wave partial (b128)
#pragma unroll
    for (int bi = 0; bi < 4; ++bi)
#pragma unroll
      for (int ri = 0; ri < 4; ++ri)
        acc[bi][ri] += __shfl_xor(acc[bi][ri], 32, 64);
    if (lane < 32) {
#pragma unroll
      for (int bi = 0; bi < 4; ++bi) {
        float4 v = make_float4(acc[bi][0], acc[bi][1], acc[bi][2], acc[bi][3]);
        *(float4*)&part[p][w][bt * 4 + bi][rt * 4] = v;
      }
    }
    barrier_lds_();  // B1: LDS-ordered barrier; global prefetch stays in flight

    if (tid < 128) {
      const int bglob = b0 + pbl;
      float gsum[4];
#pragma unroll
      for (int g = 0; g < 4; ++g) {
        const int r = g * 8 + pj;
        gsum[g] = xp[g] + ((part[p][0][pbl][r] + part[p][1][pbl][r]) +
                           (part[p][2][pbl][r] + part[p][3][pbl][r]));
      }
      float si = sigmoidf_(gsum[0]);
      float sf = sigmoidf_(gsum[1]);
      float tg = tanhf(gsum[2]);
      float so = sigmoidf_(gsum[3]);
      c_reg = sf * c_reg + si * tg;
      float h = so * tanhf(c_reg);
      unsigned long long pk =
          (((unsigned long long)(unsigned)t) << 32) |
          (unsigned long long)__float_as_uint(h);
      __hip_atomic_store(hbuf + ((size_t)((t & 1) * 2 + d)) * (256 * 64) +
                             (size_t)(s * 8 + pj) * 64 + bglob,
                         pk, __ATOMIC_RELAXED, __HIP_MEMORY_SCOPE_AGENT);
      hout_c[((size_t)(d * tc + lt) * B_ + bglob) * H_ + s * 8 + pj] = h;
    }
    // no B2: part[] is parity-double-buffered; B1 ordering protects reuse
  }

  if (tid < 128)
    cstate[((size_t)d * B_ + b0 + pbl) * H_ + s * 8 + pj] = c_reg;
}

// ============================================================================
// K3: both directions' emission contributions in one launch.
// ============================================================================
__global__ __launch_bounds__(256) void k3_emis(
    const float* __restrict__ hout_c, const float* __restrict__ Wout,
    float* __restrict__ emisF, float* __restrict__ emisB, int chunk, int tc)
{
  __shared__ float hh[8][264];
  const int tid = threadIdx.x;
  const int nt8 = tc >> 3;
  const int per_d = 64 * nt8;
  const int d   = blockIdx.x / per_d;
  const int rem = blockIdx.x % per_d;
  const int b   = rem / nt8;
  const int lt0 = (rem % nt8) * 8;
  float* emisX = d ? emisB : emisF;
  {
    int r = tid >> 5, q = tid & 31;
    const float* src = hout_c + ((size_t)(d * tc + lt0 + r) * B_ + b) * H_;
#pragma unroll
    for (int i = 0; i < 2; ++i) {
      int f4i = q + 32 * i;
      *(float4*)&hh[r][f4i * 4] = *(const float4*)(src + f4i * 4);
    }
  }
  __syncthreads();
  if (tid < 192) {
    int r = tid / 24, tag = tid % 24;
    float acc = 0.0f;
    const float* w = Wout + (size_t)tag * 512 + d * 256;
#pragma unroll 4
    for (int k4 = 0; k4 < 64; ++k4) {
      float4 wv = *(const float4*)(w + k4 * 4);
      float4 hv = *(const float4*)&hh[r][k4 * 4];
      acc = fmaf(wv.x, hv.x, acc);
      acc = fmaf(wv.y, hv.y, acc);
      acc = fmaf(wv.z, hv.z, acc);
      acc = fmaf(wv.w, hv.w, acc);
    }
    int lt = lt0 + r;
    int tok = d ? (S_ - 1 - (chunk * tc + lt)) : (chunk * tc + lt);
    emisX[((size_t)b * S_ + tok) * NT_ + tag] = acc;
  }
}

// ============================================================================
// K4: Viterbi forward + backtrack; 1 wave per batch element.
// ============================================================================
__global__ __launch_bounds__(64) void k4_viterbi(
    const float* __restrict__ emisF, const float* __restrict__ emisB,
    const float* __restrict__ bout, const unsigned char* __restrict__ mb,
    const float* __restrict__ trans, const float* __restrict__ startv,
    const float* __restrict__ endv, int* __restrict__ outp)
{
  __shared__ float tl[24 * 25];
  __shared__ float sc[24];
  __shared__ float fin[24];
  __shared__ unsigned char hist[511 * 24];
  const int b = blockIdx.x;
  const int tid = threadIdx.x;
  const int is_bool = mb[1];

  for (int i = tid; i < 576; i += 64) tl[(i / 24) * 25 + (i % 24)] = trans[i];
  if (tid < 24) {
    size_t e0 = (size_t)b * S_ * NT_ + tid;
    sc[tid] = startv[tid] + (emisF[e0] + emisB[e0] + bout[tid]);
  }
  __syncthreads();

  for (int t = 1; t < S_; ++t) {
    float best = -3.4e38f, scj = 0.f;
    int idx = 0;
    int m;
    {
      int mi = b * S_ + t;
      m = is_bool ? (int)mb[mi] : (int)mb[mi << 2];
    }
    if (tid < 24) {
      size_t ei = ((size_t)b * S_ + t) * NT_ + tid;
      float e = emisF[ei] + emisB[ei] + bout[tid];
      for (int i = 0; i < 24; ++i) {
        float v = (sc[i] + tl[i * 25 + tid]) + e;   // ref assoc order
        if (v > best) { best = v; idx = i; }
      }
      scj = sc[tid];
    }
    __syncthreads();
    if (tid < 24) {
      sc[tid] = m ? best : scj;
      hist[(t - 1) * 24 + tid] = (unsigned char)(m ? idx : tid);
    }
    __syncthreads();
  }
  if (tid < 24) fin[tid] = sc[tid] + endv[tid];
  __syncthreads();
  if (tid == 0) {
    int tag = 0; float best = fin[0];
    for (int i = 1; i < 24; ++i)
      if (fin[i] > best) { best = fin[i]; tag = i; }
    outp[b * S_ + (S_ - 1)] = tag;
    for (int tt = S_ - 2; tt >= 0; --tt) {
      tag = hist[tt * 24 + tag];
      outp[b * S_ + tt] = tag;
    }
  }
}

// ============================================================================
extern "C" void kernel_launch(void* const* d_in, const int* in_sizes, int n_in,
                              void* d_out, int out_size, void* d_ws,
                              size_t ws_size, hipStream_t stream)
{
  const int*   x      = (const int*)d_in[0];
  const unsigned char* maskb = (const unsigned char*)d_in[1];
  const float* emb    = (const float*)d_in[2];
  const float* Wih_f  = (const float*)d_in[3];
  const float* Whh_f  = (const float*)d_in[4];
  const float* bih_f  = (const float*)d_in[5];
  const float* bhh_f  = (const float*)d_in[6];
  const float* Wih_b  = (const float*)d_in[7];
  const float* Whh_b  = (const float*)d_in[8];
  const float* bih_b  = (const float*)d_in[9];
  const float* bhh_b  = (const float*)d_in[10];
  const float* Wout   = (const float*)d_in[11];
  const float* bout   = (const float*)d_in[12];
  const float* trans  = (const float*)d_in[13];
  const float* startv = (const float*)d_in[14];
  const float* endv   = (const float*)d_in[15];

  int tc = 8;
  {
    const int cand[6] = {512, 256, 128, 64, 32, 16};
    for (int i = 0; i < 6; ++i) {
      size_t needF = HOUT_OFF + (size_t)cand[i] * (2 * B_ * H_ + 2 * B_ * G4H_);
      if (needF * sizeof(float) <= ws_size) { tc = cand[i]; break; }
    }
  }
  const int nc = S_ / tc;

  float* ws     = (float*)d_ws;
  unsigned long long* hbuf = (unsigned long long*)(ws + HBUF_OFF);
  float* cstate = ws + CST_OFF;
  float* emisF  = ws + EMF_OFF;
  float* emisB  = ws + EMB_OFF;
  float* hout_c = ws + HOUT_OFF;
  float* xpre_c = hout_c + (size_t)tc * 2 * B_ * H_;

  // zero hbuf (h(0)=0, tags=0); ws is re-poisoned 0xAA before every launch
  hipMemsetAsync(d_ws, 0, 131072 * sizeof(float), stream);

  for (int c = 0; c < nc; ++c) {
    hipLaunchKernelGGL(k1_xpre, dim3(8 * tc), dim3(256), 0, stream,
                       x, emb, Wih_f, bih_f, bhh_f, Wih_b, bih_b, bhh_b,
                       xpre_c, c, tc);
    hipLaunchKernelGGL(k2_lstm, dim3(256), dim3(256), 0, stream,
                       Whh_f, Whh_b, xpre_c, hout_c, hbuf, cstate, c, tc);
    hipLaunchKernelGGL(k3_emis, dim3(2 * 64 * (tc / 8)), dim3(256), 0, stream,
                       hout_c, Wout, emisF, emisB, c, tc);
  }
  hipLaunchKernelGGL(k4_viterbi, dim3(64), dim3(64), 0, stream,
                     emisF, emisB, bout, maskb, trans, startv, endv,
                     (int*)d_out);
}

// Round 9
// 2670.337 us; speedup vs baseline: 1.6705x; 1.1986x over previous
//
#include <hip/hip_runtime.h>
#include <math.h>

#define B_   64
#define S_   512
#define E_   256
#define H_   256
#define G4H_ 1024
#define NT_  24

// ---- workspace layout (float-element offsets) ----
// hbuf : [2 slot][2 dir][256 k][64 b] x {float h, uint tag} = 131072 f (zeroed)
// cstate: [2][B][H] = 32768 f
// whi/wlo: bf16 split of Wih_f/Wih_b, [2][1024][256] ushort = 262144 f each
// emisF/emisB: [B][S][NT]; hout_c then xpre_c (tc-sized)
static const size_t HBUF_OFF  = 0;
static const size_t CST_OFF   = 131072;
static const size_t WHI_OFF   = 163840;
static const size_t WLO_OFF   = 425984;
static const size_t EMF_OFF   = 688128;
static const size_t EMB_OFF   = 1474560;
static const size_t HOUT_OFF  = 2260992;

typedef short  bf16x8_ __attribute__((ext_vector_type(8)));
typedef float  f32x4_  __attribute__((ext_vector_type(4)));

__device__ __forceinline__ float sigmoidf_(float x) {
  return 1.0f / (1.0f + expf(-x));
}

__device__ __forceinline__ unsigned short bf16_rne_(float v) {
  unsigned u = __float_as_uint(v);
  unsigned r = u + 0x7fffu + ((u >> 16) & 1u);
  return (unsigned short)(r >> 16);
}

// ============================================================================
// K0: split Wih_f/Wih_b into bf16 hi/lo planes (one-time, ~2 MB).
// grid = 512, block = 256; one float4 per thread.
// ============================================================================
__global__ __launch_bounds__(256) void k0_wconv(
    const float* __restrict__ Wf, const float* __restrict__ Wb,
    unsigned short* __restrict__ whi, unsigned short* __restrict__ wlo)
{
  int idx = blockIdx.x * 256 + threadIdx.x;  // f4 index over [2][65536]
  int d   = idx >> 16;
  int i4  = idx & 65535;
  const float* W = d ? Wb : Wf;
  float4 v = *(const float4*)(W + (size_t)i4 * 4);
  float vv[4] = {v.x, v.y, v.z, v.w};
  unsigned short h[4], l[4];
#pragma unroll
  for (int e = 0; e < 4; ++e) {
    h[e] = bf16_rne_(vv[e]);
    float hf = __uint_as_float((unsigned)h[e] << 16);
    l[e] = bf16_rne_(vv[e] - hf);
  }
  size_t o = (size_t)d * 262144 + (size_t)i4 * 4;
  whi[o + 0] = h[0]; whi[o + 1] = h[1]; whi[o + 2] = h[2]; whi[o + 3] = h[3];
  wlo[o + 0] = l[0]; wlo[o + 1] = l[1]; wlo[o + 2] = l[2]; wlo[o + 3] = l[3];
}

// ============================================================================
// K1: xpre via split-bf16 MFMA. xpre[m][n] = e[m] @ Wih^T[n] + bias[n],
// m = lt*64+b (tc*64 rows/dir), n = 1024, K = 256.
// Ozaki 2-split, all 4 cross products: err ~2^-18 rel (f32-comparable).
// WG tile 128x128, 4 waves of 64x64, K-slabs of 32 (8 slabs).
// grid = 8*tc, block = 256.
// ============================================================================
__global__ __launch_bounds__(256) void k1_xpre_mfma(
    const int* __restrict__ x, const float* __restrict__ emb,
    const unsigned short* __restrict__ whi,
    const unsigned short* __restrict__ wlo,
    const float* __restrict__ bih_f, const float* __restrict__ bhh_f,
    const float* __restrict__ bih_b, const float* __restrict__ bhh_b,
    float* __restrict__ xpre_c, int chunk, int tc)
{
  __shared__ unsigned short Ahi[128][40], Alo[128][40];  // stride 40: 16B-align
  __shared__ unsigned short Bhi[128][40], Blo[128][40];
  __shared__ int xt[128];

  const int tid = threadIdx.x;
  const int wg  = blockIdx.x;
  const int per_dir = 4 * tc;            // (tc/2) m-tiles * 8 n-tiles
  const int d   = wg / per_dir;
  const int rem = wg % per_dir;
  const int m0  = (rem >> 3) * 128;
  const int n0  = (rem & 7) * 128;
  const int t0  = chunk * tc;

  const float* bih = d ? bih_b : bih_f;
  const float* bhh = d ? bhh_b : bhh_f;
  const unsigned short* Whi = whi + (size_t)d * 262144;
  const unsigned short* Wlo = wlo + (size_t)d * 262144;

  if (tid < 128) {
    int m = m0 + tid;
    int lt = m >> 6, b = m & 63;
    int tok = d ? (S_ - 1 - (t0 + lt)) : (t0 + lt);
    xt[tid] = x[b * S_ + tok];
  }

  const int lane = tid & 63, wid = tid >> 6;
  const int wr = wid >> 1, wc = wid & 1;    // wave tile (64r x 64c)
  const int fr = lane & 15, fq = lane >> 4; // frag row/col and quad
  const int sr = tid >> 1, sh = tid & 1;    // staging row, k-half

  f32x4_ acc[4][4];
#pragma unroll
  for (int i = 0; i < 4; ++i)
#pragma unroll
    for (int j = 0; j < 4; ++j) acc[i][j] = (f32x4_){0.f, 0.f, 0.f, 0.f};

  for (int slab = 0; slab < 8; ++slab) {
    const int k0 = slab * 32;
    __syncthreads();   // covers xt[] on slab 0, prior frag reads after
    // stage A: emb row xt[sr], 16 cols, f32 -> bf16 hi/lo
    {
      const float* src = emb + (size_t)xt[sr] * E_ + k0 + sh * 16;
      unsigned short h[16], l[16];
#pragma unroll
      for (int q = 0; q < 4; ++q) {
        float4 v = *(const float4*)(src + q * 4);
        float vv[4] = {v.x, v.y, v.z, v.w};
#pragma unroll
        for (int e = 0; e < 4; ++e) {
          h[q * 4 + e] = bf16_rne_(vv[e]);
          float hf = __uint_as_float((unsigned)h[q * 4 + e] << 16);
          l[q * 4 + e] = bf16_rne_(vv[e] - hf);
        }
      }
      *(bf16x8_*)&Ahi[sr][sh * 16 + 0] = *(bf16x8_*)&h[0];
      *(bf16x8_*)&Ahi[sr][sh * 16 + 8] = *(bf16x8_*)&h[8];
      *(bf16x8_*)&Alo[sr][sh * 16 + 0] = *(bf16x8_*)&l[0];
      *(bf16x8_*)&Alo[sr][sh * 16 + 8] = *(bf16x8_*)&l[8];
    }
    // stage B: pre-split Wih rows (bf16 copy, no conversion)
    {
      const size_t o = (size_t)(n0 + sr) * E_ + k0 + sh * 16;
      *(bf16x8_*)&Bhi[sr][sh * 16 + 0] = *(const bf16x8_*)(Whi + o);
      *(bf16x8_*)&Bhi[sr][sh * 16 + 8] = *(const bf16x8_*)(Whi + o + 8);
      *(bf16x8_*)&Blo[sr][sh * 16 + 0] = *(const bf16x8_*)(Wlo + o);
      *(bf16x8_*)&Blo[sr][sh * 16 + 8] = *(const bf16x8_*)(Wlo + o + 8);
    }
    __syncthreads();

    bf16x8_ ah[4], al[4], bh[4], bl[4];
#pragma unroll
    for (int mi = 0; mi < 4; ++mi) {
      int row = 64 * wr + mi * 16 + fr;
      ah[mi] = *(bf16x8_*)&Ahi[row][fq * 8];
      al[mi] = *(bf16x8_*)&Alo[row][fq * 8];
    }
#pragma unroll
    for (int ni = 0; ni < 4; ++ni) {
      int row = 64 * wc + ni * 16 + fr;
      bh[ni] = *(bf16x8_*)&Bhi[row][fq * 8];
      bl[ni] = *(bf16x8_*)&Blo[row][fq * 8];
    }
#pragma unroll
    for (int mi = 0; mi < 4; ++mi)
#pragma unroll
      for (int ni = 0; ni < 4; ++ni) {
        acc[mi][ni] = __builtin_amdgcn_mfma_f32_16x16x32_bf16(
            al[mi], bl[ni], acc[mi][ni], 0, 0, 0);
        acc[mi][ni] = __builtin_amdgcn_mfma_f32_16x16x32_bf16(
            al[mi], bh[ni], acc[mi][ni], 0, 0, 0);
        acc[mi][ni] = __builtin_amdgcn_mfma_f32_16x16x32_bf16(
            ah[mi], bl[ni], acc[mi][ni], 0, 0, 0);
        acc[mi][ni] = __builtin_amdgcn_mfma_f32_16x16x32_bf16(
            ah[mi], bh[ni], acc[mi][ni], 0, 0, 0);
      }
  }

  // epilogue: D row = fq*4+reg (m), col = fr (n); add bias, store f32
  float bias[4];
#pragma unroll
  for (int ni = 0; ni < 4; ++ni) {
    int col = n0 + 64 * wc + ni * 16 + fr;
    bias[ni] = bih[col] + bhh[col];
  }
  const size_t base = (size_t)(d * tc * 64) * G4H_;
#pragma unroll
  for (int mi = 0; mi < 4; ++mi)
#pragma unroll
    for (int ni = 0; ni < 4; ++ni) {
      int col = n0 + 64 * wc + ni * 16 + fr;
#pragma unroll
      for (int r = 0; r < 4; ++r) {
        int m = m0 + 64 * wr + mi * 16 + fq * 4 + r;
        xpre_c[base + (size_t)m * G4H_ + col] = acc[mi][ni][r] + bias[ni];
      }
    }
}

// ============================================================================
// K2: biLSTM recurrence — EXACT round-5 structure (best measured 970 us):
// tag-in-data sync, 128B-coalesced staging, Whh in VGPRs, hTb[b][k] layout,
// part[] parity-double-buffered, single __syncthreads per step.
// 256 WGs = dir(2) x batch-group(4 x 16b) x h-slice(32 x 8 rows), 1 WG/CU.
// ============================================================================
__global__ __launch_bounds__(256, 1) void k2_lstm(
    const float* __restrict__ Whh_f, const float* __restrict__ Whh_b,
    const float* __restrict__ xpre_c, float* __restrict__ hout_c,
    unsigned long long* hbuf, float* cstate, int chunk, int tc)
{
  __shared__ float hTb[16][260];         // [b_local][k + pad]
  __shared__ float part[2][4][16][36];   // [parity][wave][b][r]

  const int tid = threadIdx.x;
  const int wg  = blockIdx.x;
  const int d   = wg >> 7;
  const int bg  = (wg >> 5) & 3;
  const int s   = wg & 31;
  const int b0  = bg * 16;
  const float* Whh = d ? Whh_b : Whh_f;

  const int w     = tid >> 6;           // wave 0..3
  const int lane  = tid & 63;
  const int bl16  = lane & 15;          // staging batch
  const int kb    = lane >> 4;          // 0..3
  const int kbase = w * 64 + kb * 16;   // staging k range [kbase, kbase+16)
  const int ks    = tid >> 5;           // GEMM k-chunk [32ks, 32ks+32)
  const int tl    = tid & 31, bt = tl & 3, rt = tl >> 2;
  const int pbl   = tid >> 3, pj = tid & 7;   // pointwise mapping (tid<128)

  // hoist this thread's Whh tile into registers (fixed for all steps)
  float wreg[4][32];
#pragma unroll
  for (int ri = 0; ri < 4; ++ri) {
    int r = rt * 4 + ri, g = r >> 3, j = r & 7;
    const float* src = Whh + ((size_t)(g * H_ + s * 8 + j)) * H_ + ks * 32;
#pragma unroll
    for (int q = 0; q < 8; ++q) {
      float4 v = *(const float4*)(src + q * 4);
      wreg[ri][q * 4 + 0] = v.x; wreg[ri][q * 4 + 1] = v.y;
      wreg[ri][q * 4 + 2] = v.z; wreg[ri][q * 4 + 3] = v.w;
    }
  }

  float c_reg = 0.0f;
  if (chunk > 0 && tid < 128)
    c_reg = cstate[((size_t)d * B_ + b0 + pbl) * H_ + s * 8 + pj];

  for (int tt = 1; tt <= tc; ++tt) {
    const int t  = chunk * tc + tt;   // global step 1..512
    const int lt = tt - 1;
    const int p  = tt & 1;

    // xpre prefetch (independent of h -> overlaps the poll)
    float xp[4];
    if (tid < 128) {
#pragma unroll
      for (int g = 0; g < 4; ++g)
        xp[g] = xpre_c[((size_t)(d * tc + lt) * B_ + b0 + pbl) * G4H_ +
                       g * H_ + s * 8 + pj];
    }

    // stage h(t-1): 16 tagged entries/lane, batched retry on stale tags
    {
      const unsigned expt = (unsigned)(t - 1);
      const unsigned long long* hb =
          hbuf + ((size_t)(((t - 1) & 1) * 2 + d)) * (256 * 64);
      const size_t a0 = (size_t)kbase * 64 + b0 + bl16;
      unsigned long long e[16];
#pragma unroll
      for (int i = 0; i < 16; ++i)
        e[i] = __hip_atomic_load(hb + a0 + (size_t)i * 64,
                                 __ATOMIC_RELAXED, __HIP_MEMORY_SCOPE_AGENT);
      int lim = 0;
      while (true) {
        unsigned bad = 0;
#pragma unroll
        for (int i = 0; i < 16; ++i)
          if ((unsigned)(e[i] >> 32) != expt) bad |= (1u << i);
        if (bad == 0) break;
        if (++lim > (1 << 18)) break;   // deadlock safety
#pragma unroll
        for (int i = 0; i < 16; ++i)
          if (bad & (1u << i))
            e[i] = __hip_atomic_load(hb + a0 + (size_t)i * 64,
                                     __ATOMIC_RELAXED,
                                     __HIP_MEMORY_SCOPE_AGENT);
      }
      float4 v0, v1, v2, v3;
      v0.x = __uint_as_float((unsigned)e[0]);  v0.y = __uint_as_float((unsigned)e[1]);
      v0.z = __uint_as_float((unsigned)e[2]);  v0.w = __uint_as_float((unsigned)e[3]);
      v1.x = __uint_as_float((unsigned)e[4]);  v1.y = __uint_as_float((unsigned)e[5]);
      v1.z = __uint_as_float((unsigned)e[6]);  v1.w = __uint_as_float((unsigned)e[7]);
      v2.x = __uint_as_float((unsigned)e[8]);  v2.y = __uint_as_float((unsigned)e[9]);
      v2.z = __uint_as_float((unsigned)e[10]); v2.w = __uint_as_float((unsigned)e[11]);
      v3.x = __uint_as_float((unsigned)e[12]); v3.y = __uint_as_float((unsigned)e[13]);
      v3.z = __uint_as_float((unsigned)e[14]); v3.w = __uint_as_float((unsigned)e[15]);
      *(float4*)&hTb[bl16][kbase +  0] = v0;
      *(float4*)&hTb[bl16][kbase +  4] = v1;
      *(float4*)&hTb[bl16][kbase +  8] = v2;
      *(float4*)&hTb[bl16][kbase + 12] = v3;
    }
    // no barrier: wave GEMM-reads only its own staged k-columns

    // GEMM: acc[bi][ri] += h[b][k] * W[k][r], weights from VGPRs
    float acc[4][4];
#pragma unroll
    for (int bi = 0; bi < 4; ++bi)
#pragma unroll
      for (int ri = 0; ri < 4; ++ri) acc[bi][ri] = 0.0f;
#pragma unroll
    for (int kq = 0; kq < 8; ++kq) {
      const int k0 = ks * 32 + kq * 4;
      float4 h4[4];
#pragma unroll
      for (int bi = 0; bi < 4; ++bi)
        h4[bi] = *(float4*)&hTb[bt * 4 + bi][k0];
#pragma unroll
      for (int kk = 0; kk < 4; ++kk) {
#pragma unroll
        for (int bi = 0; bi < 4; ++bi) {
          const float hv = kk == 0 ? h4[bi].x : kk == 1 ? h4[bi].y
                         : kk == 2 ? h4[bi].z : h4[bi].w;
#pragma unroll
          for (int ri = 0; ri < 4; ++ri)
            acc[bi][ri] = fmaf(hv, wreg[ri][kq * 4 + kk], acc[bi][ri]);
        }
      }
    }
    // reduce the two half-wave k-chunks, publish wave partial (b128)
#pragma unroll
    for (int bi = 0; bi < 4; ++bi)
#pragma unroll
      for (int ri = 0; ri < 4; ++ri)
        acc[bi][ri] += __shfl_xor(acc[bi][ri], 32, 64);
    if (lane < 32) {
#pragma unroll
      for (int bi = 0; bi < 4; ++bi) {
        float4 v = make_float4(acc[bi][0], acc[bi][1], acc[bi][2], acc[bi][3]);
        *(float4*)&part[p][w][bt * 4 + bi][rt * 4] = v;
      }
    }
    __syncthreads();   // B1: wave partials visible to pointwise waves

    if (tid < 128) {
      const int bglob = b0 + pbl;
      float gsum[4];
#pragma unroll
      for (int g = 0; g < 4; ++g) {
        const int r = g * 8 + pj;
        gsum[g] = xp[g] + ((part[p][0][pbl][r] + part[p][1][pbl][r]) +
                           (part[p][2][pbl][r] + part[p][3][pbl][r]));
      }
      float si = sigmoidf_(gsum[0]);
      float sf = sigmoidf_(gsum[1]);
      float tg = tanhf(gsum[2]);
      float so = sigmoidf_(gsum[3]);
      c_reg = sf * c_reg + si * tg;
      float h = so * tanhf(c_reg);
      unsigned long long pk =
          (((unsigned long long)(unsigned)t) << 32) |
          (unsigned long long)__float_as_uint(h);
      __hip_atomic_store(hbuf + ((size_t)((t & 1) * 2 + d)) * (256 * 64) +
                             (size_t)(s * 8 + pj) * 64 + bglob,
                         pk, __ATOMIC_RELAXED, __HIP_MEMORY_SCOPE_AGENT);
      hout_c[((size_t)(d * tc + lt) * B_ + bglob) * H_ + s * 8 + pj] = h;
    }
    // no B2: part is parity-double-buffered; B1 ordering protects reuse
  }

  if (tid < 128)
    cstate[((size_t)d * B_ + b0 + pbl) * H_ + s * 8 + pj] = c_reg;
}

// ============================================================================
// K3: both directions' emission contributions in one launch.
// ============================================================================
__global__ __launch_bounds__(256) void k3_emis(
    const float* __restrict__ hout_c, const float* __restrict__ Wout,
    float* __restrict__ emisF, float* __restrict__ emisB, int chunk, int tc)
{
  __shared__ float hh[8][264];
  const int tid = threadIdx.x;
  const int nt8 = tc >> 3;
  const int per_d = 64 * nt8;
  const int d   = blockIdx.x / per_d;
  const int rem = blockIdx.x % per_d;
  const int b   = rem / nt8;
  const int lt0 = (rem % nt8) * 8;
  float* emisX = d ? emisB : emisF;
  {
    int r = tid >> 5, q = tid & 31;
    const float* src = hout_c + ((size_t)(d * tc + lt0 + r) * B_ + b) * H_;
#pragma unroll
    for (int i = 0; i < 2; ++i) {
      int f4i = q + 32 * i;
      *(float4*)&hh[r][f4i * 4] = *(const float4*)(src + f4i * 4);
    }
  }
  __syncthreads();
  if (tid < 192) {
    int r = tid / 24, tag = tid % 24;
    float acc = 0.0f;
    const float* w = Wout + (size_t)tag * 512 + d * 256;
#pragma unroll 4
    for (int k4 = 0; k4 < 64; ++k4) {
      float4 wv = *(const float4*)(w + k4 * 4);
      float4 hv = *(const float4*)&hh[r][k4 * 4];
      acc = fmaf(wv.x, hv.x, acc);
      acc = fmaf(wv.y, hv.y, acc);
      acc = fmaf(wv.z, hv.z, acc);
      acc = fmaf(wv.w, hv.w, acc);
    }
    int lt = lt0 + r;
    int tok = d ? (S_ - 1 - (chunk * tc + lt)) : (chunk * tc + lt);
    emisX[((size_t)b * S_ + tok) * NT_ + tag] = acc;
  }
}

// ============================================================================
// K4: Viterbi forward + backtrack; 1 wave per batch element.
// ============================================================================
__global__ __launch_bounds__(64) void k4_viterbi(
    const float* __restrict__ emisF, const float* __restrict__ emisB,
    const float* __restrict__ bout, const unsigned char* __restrict__ mb,
    const float* __restrict__ trans, const float* __restrict__ startv,
    const float* __restrict__ endv, int* __restrict__ outp)
{
  __shared__ float tl[24 * 25];
  __shared__ float sc[24];
  __shared__ float fin[24];
  __shared__ unsigned char hist[511 * 24];
  const int b = blockIdx.x;
  const int tid = threadIdx.x;
  const int is_bool = mb[1];

  for (int i = tid; i < 576; i += 64) tl[(i / 24) * 25 + (i % 24)] = trans[i];
  if (tid < 24) {
    size_t e0 = (size_t)b * S_ * NT_ + tid;
    sc[tid] = startv[tid] + (emisF[e0] + emisB[e0] + bout[tid]);
  }
  __syncthreads();

  for (int t = 1; t < S_; ++t) {
    float best = -3.4e38f, scj = 0.f;
    int idx = 0;
    int m;
    {
      int mi = b * S_ + t;
      m = is_bool ? (int)mb[mi] : (int)mb[mi << 2];
    }
    if (tid < 24) {
      size_t ei = ((size_t)b * S_ + t) * NT_ + tid;
      float e = emisF[ei] + emisB[ei] + bout[tid];
      for (int i = 0; i < 24; ++i) {
        float v = (sc[i] + tl[i * 25 + tid]) + e;   // ref assoc order
        if (v > best) { best = v; idx = i; }
      }
      scj = sc[tid];
    }
    __syncthreads();
    if (tid < 24) {
      sc[tid] = m ? best : scj;
      hist[(t - 1) * 24 + tid] = (unsigned char)(m ? idx : tid);
    }
    __syncthreads();
  }
  if (tid < 24) fin[tid] = sc[tid] + endv[tid];
  __syncthreads();
  if (tid == 0) {
    int tag = 0; float best = fin[0];
    for (int i = 1; i < 24; ++i)
      if (fin[i] > best) { best = fin[i]; tag = i; }
    outp[b * S_ + (S_ - 1)] = tag;
    for (int tt = S_ - 2; tt >= 0; --tt) {
      tag = hist[tt * 24 + tag];
      outp[b * S_ + tt] = tag;
    }
  }
}

// ============================================================================
extern "C" void kernel_launch(void* const* d_in, const int* in_sizes, int n_in,
                              void* d_out, int out_size, void* d_ws,
                              size_t ws_size, hipStream_t stream)
{
  const int*   x      = (const int*)d_in[0];
  const unsigned char* maskb = (const unsigned char*)d_in[1];
  const float* emb    = (const float*)d_in[2];
  const float* Wih_f  = (const float*)d_in[3];
  const float* Whh_f  = (const float*)d_in[4];
  const float* bih_f  = (const float*)d_in[5];
  const float* bhh_f  = (const float*)d_in[6];
  const float* Wih_b  = (const float*)d_in[7];
  const float* Whh_b  = (const float*)d_in[8];
  const float* bih_b  = (const float*)d_in[9];
  const float* bhh_b  = (const float*)d_in[10];
  const float* Wout   = (const float*)d_in[11];
  const float* bout   = (const float*)d_in[12];
  const float* trans  = (const float*)d_in[13];
  const float* startv = (const float*)d_in[14];
  const float* endv   = (const float*)d_in[15];

  int tc = 8;
  {
    const int cand[6] = {512, 256, 128, 64, 32, 16};
    for (int i = 0; i < 6; ++i) {
      size_t needF = HOUT_OFF + (size_t)cand[i] * (2 * B_ * H_ + 2 * B_ * G4H_);
      if (needF * sizeof(float) <= ws_size) { tc = cand[i]; break; }
    }
  }
  const int nc = S_ / tc;

  float* ws     = (float*)d_ws;
  unsigned long long* hbuf = (unsigned long long*)(ws + HBUF_OFF);
  float* cstate = ws + CST_OFF;
  unsigned short* whi = (unsigned short*)(ws + WHI_OFF);
  unsigned short* wlo = (unsigned short*)(ws + WLO_OFF);
  float* emisF  = ws + EMF_OFF;
  float* emisB  = ws + EMB_OFF;
  float* hout_c = ws + HOUT_OFF;
  float* xpre_c = hout_c + (size_t)tc * 2 * B_ * H_;

  // zero hbuf (h(0)=0, tags=0); ws is re-poisoned 0xAA before every launch
  hipMemsetAsync(d_ws, 0, 131072 * sizeof(float), stream);
  hipLaunchKernelGGL(k0_wconv, dim3(512), dim3(256), 0, stream,
                     Wih_f, Wih_b, whi, wlo);

  for (int c = 0; c < nc; ++c) {
    hipLaunchKernelGGL(k1_xpre_mfma, dim3(8 * tc), dim3(256), 0, stream,
                       x, emb, whi, wlo, bih_f, bhh_f, bih_b, bhh_b,
                       xpre_c, c, tc);
    hipLaunchKernelGGL(k2_lstm, dim3(256), dim3(256), 0, stream,
                       Whh_f, Whh_b, xpre_c, hout_c, hbuf, cstate, c, tc);
    hipLaunchKernelGGL(k3_emis, dim3(2 * 64 * (tc / 8)), dim3(256), 0, stream,
                       hout_c, Wout, emisF, emisB, c, tc);
  }
  hipLaunchKernelGGL(k4_viterbi, dim3(64), dim3(64), 0, stream,
                     emisF, emisB, bout, maskb, trans, startv, endv,
                     (int*)d_out);
}